// Round 8
// baseline (413.930 us; speedup 1.0000x reference)
//
#include <hip/hip_runtime.h>
#include <cstdint>
#include <cstddef>

#define B_  2
#define H_  8
#define C_  2048
#define HW_ 64
#define HD_ 512   // H_*HW_

typedef __attribute__((ext_vector_type(8))) short short8;
typedef __attribute__((ext_vector_type(4))) short short4v;
typedef __attribute__((ext_vector_type(4))) float f32x4;
typedef __attribute__((ext_vector_type(4))) int   int4v;
typedef unsigned short us;

static __device__ inline us f2bf(float f) {           // RNE
    unsigned u = __builtin_bit_cast(unsigned, f);
    u = u + 0x7FFFu + ((u >> 16) & 1u);
    return (us)(u >> 16);
}
static __device__ inline us f2bf_t(float f) {         // truncate (hot path)
    return (us)(__builtin_bit_cast(unsigned, f) >> 16);
}
static __device__ inline float bf2f(us s) {
    unsigned u = ((unsigned)s) << 16;
    return __builtin_bit_cast(float, u);
}
static __device__ inline f32x4 mfma16(short8 a, short8 b, f32x4 c) {
    return __builtin_amdgcn_mfma_f32_16x16x32_bf16(a, b, c, 0, 0, 0);
}
static __device__ inline short8 negbf(short8 v) {
    int4v u = __builtin_bit_cast(int4v, v);
    u ^= (int)0x80008000;
    return __builtin_bit_cast(short8, u);
}

// ---------------- Projection + rotary phase ----------------
__global__ __launch_bounds__(256) void proj_kernel(
    const float* __restrict__ x, const float* __restrict__ WQ,
    const float* __restrict__ WK, const float* __restrict__ WV,
    const float* __restrict__ theta,
    us* __restrict__ Qch, us* __restrict__ Qcl,
    us* __restrict__ K1h, us* __restrict__ K1l,
    us* __restrict__ VTh, us* __restrict__ VTl)
{
    __shared__ float smem[3 * 64 * 65 + 32 * 65];
    float* sW = smem;               // [3][64][65]
    float* sx = smem + 3 * 64 * 65; // [32][65]
    int tid = threadIdx.x;
    int bh = blockIdx.y; int h = bh & 7;
    int c0 = blockIdx.x * 32;
    for (int t = tid; t < 64 * 64; t += 256) {
        int j = t & 63, i = t >> 6;
        int g = (h * 64 + i) * 64 + j;
        sW[0 * 64 * 65 + i * 65 + j] = WQ[g];
        sW[1 * 64 * 65 + i * 65 + j] = WK[g];
        sW[2 * 64 * 65 + i * 65 + j] = WV[g];
    }
    for (int t = tid; t < 32 * 64; t += 256) {
        int i = t & 63, c = t >> 6;
        sx[c * 65 + i] = x[((size_t)((bh >> 3) * C_ + c0 + c)) * HD_ + h * 64 + i];
    }
    __syncthreads();
    int j = tid & 63, cg = tid >> 6;
    float aq[8] = {}, ak[8] = {}, av[8] = {};
    for (int i = 0; i < 64; ++i) {
        float w0 = sW[0 * 64 * 65 + i * 65 + j];
        float w1 = sW[1 * 64 * 65 + i * 65 + j];
        float w2 = sW[2 * 64 * 65 + i * 65 + j];
        #pragma unroll
        for (int cc = 0; cc < 8; ++cc) {
            float xv = sx[(cg * 8 + cc) * 65 + i];
            aq[cc] += xv * w0;
            ak[cc] += xv * w1;
            av[cc] += xv * w2;
        }
    }
    float th = theta[h * 64 + j];
    #pragma unroll
    for (int cc = 0; cc < 8; ++cc) {
        int c = c0 + cg * 8 + cc;
        float sn, cs;
        sincosf((float)c * th, &sn, &cs);
        float qr = aq[cc] * cs, qi = aq[cc] * sn;
        float kr = ak[cc] * cs, nki = ak[cc] * sn;   // nki = -Ki
        size_t rq = ((size_t)bh * C_ + c) * 128;
        us h0;
        h0 = f2bf(qr);  Qch[rq + j]      = h0; Qcl[rq + j]      = f2bf(qr  - bf2f(h0));
        h0 = f2bf(qi);  Qch[rq + 64 + j] = h0; Qcl[rq + 64 + j] = f2bf(qi  - bf2f(h0));
        h0 = f2bf(kr);  K1h[rq + j]      = h0; K1l[rq + j]      = f2bf(kr  - bf2f(h0));
        h0 = f2bf(nki); K1h[rq + 64 + j] = h0; K1l[rq + 64 + j] = f2bf(nki - bf2f(h0));
    }
    __syncthreads();
    float* T0 = smem;                   // [64][33]
    #pragma unroll
    for (int cc = 0; cc < 8; ++cc)
        T0[j * 33 + cg * 8 + cc] = av[cc];
    __syncthreads();
    int cc2 = tid & 31, jg = tid >> 5;
    #pragma unroll
    for (int jj = 0; jj < 8; ++jj) {
        int jr = jg * 8 + jj;
        float v = T0[jr * 33 + cc2];
        us hh = f2bf(v);
        size_t o = ((size_t)bh * 64 + jr) * C_ + c0 + cc2;
        VTh[o] = hh;
        VTl[o] = f2bf(v - bf2f(hh));
    }
}

// ---------------- MFMA Retention (split-K partials) ----------------
// 768 blocks, 48 KB LDS -> 3 blocks/CU, all co-resident.
// XOR-swizzled LDS layout: element (row, col) at row*64 + ((col>>3)^(row&7))*8
// + (col&7) -> b128 staging writes + b128 frag reads, <=2-way banks.
// K B-frags register-double-buffered across nt (hide L2 latency).
// Complete parts (qt<=15) normalize + write A1 directly; split parts -> Pbuf.
__global__ __launch_bounds__(256, 3) void retention_kernel(
    const us* __restrict__ Qch, const us* __restrict__ Qcl,
    const us* __restrict__ K1h, const us* __restrict__ K1l,
    const us* __restrict__ VTh, const us* __restrict__ VTl,
    float* __restrict__ Pbuf,
    us* __restrict__ A1h, us* __restrict__ A1l,
    const float* __restrict__ gamma, const float* __restrict__ qk_scale)
{
    constexpr int PL = 64 * 64;        // plane size (shorts)
    __shared__ us smem[6 * PL];        // 48 KB
    us* sSrh = smem;
    us* sSrl = smem + PL;
    us* sSih = smem + 2 * PL;
    us* sSil = smem + 3 * PL;
    us* sVh  = smem + 4 * PL;
    us* sVl  = smem + 5 * PL;

    const int tid = threadIdx.x;
    const int w = tid >> 6, lane = tid & 63;
    const int ln = lane & 15, quad = lane >> 4;
    const int r = (int)blockIdx.x >> 4, bh = (int)blockIdx.x & 15;
    const int h = bh & 7;
    int qt, klo, slot;
    if (r == 0)       { qt = 15; klo = 0;  slot = 15; }
    else if (r == 1)  { qt = 31; klo = 16; slot = 47; }
    else if (r <= 17) { qt = 14 + r; klo = 0; slot = 16 + 2 * (qt - 16); }
    else {
        int u = r - 18, s = 15 - (u >> 1);
        if ((u & 1) == 0) { qt = s - 1;  klo = 0;  slot = qt; }
        else              { qt = 15 + s; klo = 16; slot = 17 + 2 * (qt - 16); }
    }
    const int khi = (qt >= 16 && klo == 0) ? 15 : qt;
    const int qc0 = qt * 64;
    const float lg = log2f(gamma[h]);
    const float inv_scale = 1.0f / qk_scale[0];
    float rowf[4], colf[4];
    #pragma unroll
    for (int rr2 = 0; rr2 < 4; ++rr2)
        rowf[rr2] = exp2f(lg * (float)(w * 16 + quad * 4 + rr2));
    #pragma unroll
    for (int nt = 0; nt < 4; ++nt)
        colf[nt] = exp2f(-lg * (float)(nt * 16 + ln));

    short8 Qh[4], Ql[4];
    {
        size_t qrow = ((size_t)bh * C_ + qc0 + w * 16 + ln) * 128;
        #pragma unroll
        for (int ck = 0; ck < 4; ++ck) {
            size_t off = qrow + ck * 32 + quad * 8;
            Qh[ck] = *(const short8*)(Qch + off);
            Ql[ck] = *(const short8*)(Qcl + off);
        }
    }
    f32x4 zz = {0.0f, 0.0f, 0.0f, 0.0f};
    f32x4 Or[4], Oi[4];
    #pragma unroll
    for (int it = 0; it < 4; ++it) { Or[it] = zz; Oi[it] = zz; }

    const size_t vtb = (size_t)bh * 64 * C_;
    for (int kt = klo; kt <= khi; ++kt) {
        const int kc0 = kt * 64;
        __syncthreads();   // prev phase-B reads done
        // stage V^T tile, swizzled, b128 writes
        {
            int i = tid >> 2, s2 = (tid & 3) * 2, xs = i & 7;
            size_t g = vtb + (size_t)i * C_ + kc0 + s2 * 8;
            int a0 = i * 64 + ((s2 ^ xs) * 8);
            int a1 = i * 64 + (((s2 + 1) ^ xs) * 8);
            *(short8*)&sVh[a0] = *(const short8*)(VTh + g);
            *(short8*)&sVh[a1] = *(const short8*)(VTh + g + 8);
            *(short8*)&sVl[a0] = *(const short8*)(VTl + g);
            *(short8*)&sVl[a1] = *(const short8*)(VTl + g + 8);
        }
        const float tf = exp2f(lg * (float)(qc0 - kc0)) * inv_scale;
        float tr[4];
        #pragma unroll
        for (int rr2 = 0; rr2 < 4; ++rr2) tr[rr2] = tf * rowf[rr2];
        const bool diag = (kt == qt);
        // phase A with register-double-buffered K B-frags
        short8 Kb[2][2][4];   // [buf][h=0/l=1][ck]
        {
            size_t krow = ((size_t)bh * C_ + kc0 + ln) * 128;
            #pragma unroll
            for (int ck = 0; ck < 4; ++ck) {
                size_t off = krow + ck * 32 + quad * 8;
                Kb[0][0][ck] = *(const short8*)(K1h + off);
                Kb[0][1][ck] = *(const short8*)(K1l + off);
            }
        }
        #pragma unroll
        for (int nt = 0; nt < 4; ++nt) {
            const int cur = nt & 1, nxt = cur ^ 1;
            if (nt < 3) {
                size_t krow = ((size_t)bh * C_ + kc0 + (nt + 1) * 16 + ln) * 128;
                #pragma unroll
                for (int ck = 0; ck < 4; ++ck) {
                    size_t off = krow + ck * 32 + quad * 8;
                    Kb[nxt][0][ck] = *(const short8*)(K1h + off);
                    Kb[nxt][1][ck] = *(const short8*)(K1l + off);
                }
            }
            f32x4 sr = zz, si = zz;
            short8 nKh2 = negbf(Kb[cur][0][2]), nKh3 = negbf(Kb[cur][0][3]);
            short8 nKl2 = negbf(Kb[cur][1][2]), nKl3 = negbf(Kb[cur][1][3]);
            // interleaved sr/si chains (2-way MFMA ILP)
            sr = mfma16(Qh[0], Kb[cur][0][0], sr); si = mfma16(Qh[0], nKh2, si);
            sr = mfma16(Qh[1], Kb[cur][0][1], sr); si = mfma16(Qh[1], nKh3, si);
            sr = mfma16(Qh[2], Kb[cur][0][2], sr); si = mfma16(Qh[2], Kb[cur][0][0], si);
            sr = mfma16(Qh[3], Kb[cur][0][3], sr); si = mfma16(Qh[3], Kb[cur][0][1], si);
            sr = mfma16(Qh[0], Kb[cur][1][0], sr); si = mfma16(Qh[0], nKl2, si);
            sr = mfma16(Qh[1], Kb[cur][1][1], sr); si = mfma16(Qh[1], nKl3, si);
            sr = mfma16(Qh[2], Kb[cur][1][2], sr); si = mfma16(Qh[2], Kb[cur][1][0], si);
            sr = mfma16(Qh[3], Kb[cur][1][3], sr); si = mfma16(Qh[3], Kb[cur][1][1], si);
            sr = mfma16(Ql[0], Kb[cur][0][0], sr); si = mfma16(Ql[0], nKh2, si);
            sr = mfma16(Ql[1], Kb[cur][0][1], sr); si = mfma16(Ql[1], nKh3, si);
            sr = mfma16(Ql[2], Kb[cur][0][2], sr); si = mfma16(Ql[2], Kb[cur][0][0], si);
            sr = mfma16(Ql[3], Kb[cur][0][3], sr); si = mfma16(Ql[3], Kb[cur][0][1], si);
            // decay + causal mask; truncating split; swizzled store
            const int kL = nt * 16 + ln;
            const int chnk = nt * 2 + (ln >> 3);
            const int l7 = ln & 7;
            #pragma unroll
            for (int rr2 = 0; rr2 < 4; ++rr2) {
                float wv = tr[rr2] * colf[nt];
                if (diag && (w * 16 + quad * 4 + rr2 < kL)) wv = 0.0f;
                float a = sr[rr2] * wv, c = si[rr2] * wv;
                int q = w * 16 + quad * 4 + rr2;
                int ad = q * 64 + ((chnk ^ (q & 7)) * 8) + l7;
                us h0 = f2bf_t(a); sSrh[ad] = h0; sSrl[ad] = f2bf_t(a - bf2f(h0));
                us h1 = f2bf_t(c); sSih[ad] = h1; sSil[ad] = f2bf_t(c - bf2f(h1));
            }
        }
        __syncthreads();
        // phase B: O[q][i] += S[q][kc] * V[kc][i]; b128 swizzled frag reads
        short8 SrH[2], SrL[2], SiH[2], SiL[2];
        {
            int row = w * 16 + ln, xb = ln & 7;
            #pragma unroll
            for (int ck2 = 0; ck2 < 2; ++ck2) {
                int ad = row * 64 + (((ck2 * 4 + quad) ^ xb) * 8);
                SrH[ck2] = *(const short8*)&sSrh[ad];
                SrL[ck2] = *(const short8*)&sSrl[ad];
                SiH[ck2] = *(const short8*)&sSih[ad];
                SiL[ck2] = *(const short8*)&sSil[ad];
            }
        }
        #pragma unroll
        for (int it = 0; it < 4; ++it) {
            int row = it * 16 + ln, xb = ln & 7;
            #pragma unroll
            for (int ck2 = 0; ck2 < 2; ++ck2) {
                int ad = row * 64 + (((ck2 * 4 + quad) ^ xb) * 8);
                short8 Vh = *(const short8*)&sVh[ad];
                short8 Vl = *(const short8*)&sVl[ad];
                Or[it] = mfma16(SrH[ck2], Vh, Or[it]);
                Or[it] = mfma16(SrH[ck2], Vl, Or[it]);
                Or[it] = mfma16(SrL[ck2], Vh, Or[it]);
                Oi[it] = mfma16(SiH[ck2], Vh, Oi[it]);
                Oi[it] = mfma16(SiH[ck2], Vl, Oi[it]);
                Oi[it] = mfma16(SiL[ck2], Vh, Oi[it]);
            }
        }
    }
    if (klo == 0 && khi == qt) {
        // complete part: L2-normalize and write A1 bf16 h/l directly
        float rn[4];
        #pragma unroll
        for (int rr2 = 0; rr2 < 4; ++rr2) {
            float ss = 0.0f;
            #pragma unroll
            for (int it = 0; it < 4; ++it)
                ss += Or[it][rr2] * Or[it][rr2] + Oi[it][rr2] * Oi[it][rr2];
            ss += __shfl_xor(ss, 1);
            ss += __shfl_xor(ss, 2);
            ss += __shfl_xor(ss, 4);
            ss += __shfl_xor(ss, 8);
            rn[rr2] = rsqrtf(ss);
        }
        const int b = bh >> 3;
        const size_t N1 = (size_t)B_ * H_ * C_ * HW_;
        #pragma unroll
        for (int it = 0; it < 4; ++it) {
            #pragma unroll
            for (int rr2 = 0; rr2 < 4; ++rr2) {
                int q = qc0 + w * 16 + quad * 4 + rr2;
                int i = it * 16 + ln;
                size_t o = (((size_t)(b * C_ + q)) * H_ + h) * HW_ + i;
                float vr = Or[it][rr2] * rn[rr2];
                float vi = Oi[it][rr2] * rn[rr2];
                us hh = f2bf(vr); A1h[o] = hh;      A1l[o] = f2bf(vr - bf2f(hh));
                hh = f2bf(vi);    A1h[N1 + o] = hh; A1l[N1 + o] = f2bf(vi - bf2f(hh));
            }
        }
    } else {
        float* Pr = Pbuf + ((size_t)(bh * 48 + slot)) * 8192;
        float* Pi = Pr + 4096;
        #pragma unroll
        for (int it = 0; it < 4; ++it) {
            #pragma unroll
            for (int rr2 = 0; rr2 < 4; ++rr2) {
                int qL = w * 16 + quad * 4 + rr2, iX = it * 16 + ln;
                Pr[qL * 64 + iX] = Or[it][rr2];
                Pi[qL * 64 + iX] = Oi[it][rr2];
            }
        }
    }
}

// ---------------- Partial reduce (qt>=16 only) + L2 norm -> A1 bf16 h/l ----
__global__ __launch_bounds__(256) void reduce_kernel(
    const float* __restrict__ Pbuf,
    us* __restrict__ A1h, us* __restrict__ A1l)
{
    const int qt = 16 + (int)blockIdx.x, bh = blockIdx.y;
    const int h = bh & 7, b = bh >> 3;
    const int t = threadIdx.x;
    const int q = t >> 2, i0 = (t & 3) * 16;
    const int slot0 = 16 + 2 * (int)blockIdx.x;
    const float* P0 = Pbuf + ((size_t)(bh * 48 + slot0)) * 8192 + q * 64 + i0;
    const float* P1 = P0 + 8192;
    float orv[16], oiv[16];
    #pragma unroll
    for (int s4 = 0; s4 < 4; ++s4) {
        float4 a0 = *(const float4*)(P0 + s4 * 4);
        float4 c0 = *(const float4*)(P0 + 4096 + s4 * 4);
        float4 a1 = *(const float4*)(P1 + s4 * 4);
        float4 c1 = *(const float4*)(P1 + 4096 + s4 * 4);
        orv[s4 * 4]     = a0.x + a1.x; orv[s4 * 4 + 1] = a0.y + a1.y;
        orv[s4 * 4 + 2] = a0.z + a1.z; orv[s4 * 4 + 3] = a0.w + a1.w;
        oiv[s4 * 4]     = c0.x + c1.x; oiv[s4 * 4 + 1] = c0.y + c1.y;
        oiv[s4 * 4 + 2] = c0.z + c1.z; oiv[s4 * 4 + 3] = c0.w + c1.w;
    }
    float ss = 0.0f;
    #pragma unroll
    for (int k = 0; k < 16; ++k) ss += orv[k] * orv[k] + oiv[k] * oiv[k];
    ss += __shfl_xor(ss, 1);
    ss += __shfl_xor(ss, 2);
    float rn = rsqrtf(ss);
    const size_t N1 = (size_t)B_ * H_ * C_ * HW_;
    size_t o = (((size_t)(b * C_ + qt * 64 + q)) * H_ + h) * HW_ + i0;
    us th[16], tl[16];
    #pragma unroll
    for (int k = 0; k < 16; ++k) {
        float v = orv[k] * rn;
        us hh = f2bf(v); th[k] = hh; tl[k] = f2bf(v - bf2f(hh));
    }
    *(short8*)&A1h[o] = *(short8*)&th[0]; *(short8*)&A1h[o + 8] = *(short8*)&th[8];
    *(short8*)&A1l[o] = *(short8*)&tl[0]; *(short8*)&A1l[o + 8] = *(short8*)&tl[8];
    #pragma unroll
    for (int k = 0; k < 16; ++k) {
        float v = oiv[k] * rn;
        us hh = f2bf(v); th[k] = hh; tl[k] = f2bf(v - bf2f(hh));
    }
    *(short8*)&A1h[N1 + o] = *(short8*)&th[0]; *(short8*)&A1h[N1 + o + 8] = *(short8*)&th[8];
    *(short8*)&A1l[N1 + o] = *(short8*)&tl[0]; *(short8*)&A1l[N1 + o + 8] = *(short8*)&tl[8];
}

// ---------------- Weight transpose + bf16 split: WT[n][k] = W[k][n] --------
__global__ __launch_bounds__(256) void wcvt_kernel(
    const float* __restrict__ WG, const float* __restrict__ WO,
    us* __restrict__ Gh, us* __restrict__ Gl,
    us* __restrict__ Oh, us* __restrict__ Ol)
{
    __shared__ float T[32 * 33];
    const float* src = blockIdx.z ? WO : WG;
    us* dh = blockIdx.z ? Oh : Gh;
    us* dl = blockIdx.z ? Ol : Gl;
    int k0 = blockIdx.x * 32, n0 = blockIdx.y * 32;
    int c = threadIdx.x & 31, r8 = threadIdx.x >> 5;
    #pragma unroll
    for (int rr = 0; rr < 4; ++rr) {
        int r = r8 * 4 + rr;
        T[r * 33 + c] = src[(size_t)(k0 + r) * 512 + n0 + c];
    }
    __syncthreads();
    #pragma unroll
    for (int rr = 0; rr < 4; ++rr) {
        int r = r8 * 4 + rr;            // n-local
        float v = T[c * 33 + r];        // [k-local = c][n-local = r]
        us hh = f2bf(v);
        size_t o = (size_t)(n0 + r) * 512 + k0 + c;
        dh[o] = hh; dl[o] = f2bf(v - bf2f(hh));
    }
}

// ---------------- split-bf16 MFMA GEMM: C[8192,512] = A * W (WT given) -----
__global__ __launch_bounds__(256) void gemm_mfma_kernel(
    const us* __restrict__ Ah, const us* __restrict__ Al,
    const us* __restrict__ BTh, const us* __restrict__ BTl,
    float* __restrict__ Cout, int mode)
{
    const int tid = threadIdx.x;
    const int w = tid >> 6, lane = tid & 63;
    const int ln = lane & 15, quad = lane >> 4;
    const int bm = blockIdx.x * 128 + w * 32;
    const int bn = blockIdx.y * 64;
    f32x4 acc[2][4];
    #pragma unroll
    for (int mt = 0; mt < 2; ++mt)
        #pragma unroll
        for (int nt = 0; nt < 4; ++nt) acc[mt][nt] = (f32x4){0.f, 0.f, 0.f, 0.f};
    const us* pA[2][2];
    const us* pB[4][2];
    #pragma unroll
    for (int mt = 0; mt < 2; ++mt) {
        size_t r = (size_t)(bm + mt * 16 + ln) * 512 + quad * 8;
        pA[mt][0] = Ah + r; pA[mt][1] = Al + r;
    }
    #pragma unroll
    for (int nt = 0; nt < 4; ++nt) {
        size_t r = (size_t)(bn + nt * 16 + ln) * 512 + quad * 8;
        pB[nt][0] = BTh + r; pB[nt][1] = BTl + r;
    }
    #pragma unroll
    for (int ks = 0; ks < 16; ++ks) {
        const int ko = ks * 32;
        short8 Af[2][2], Bf[4][2];
        #pragma unroll
        for (int mt = 0; mt < 2; ++mt) {
            Af[mt][0] = *(const short8*)(pA[mt][0] + ko);
            Af[mt][1] = *(const short8*)(pA[mt][1] + ko);
        }
        #pragma unroll
        for (int nt = 0; nt < 4; ++nt) {
            Bf[nt][0] = *(const short8*)(pB[nt][0] + ko);
            Bf[nt][1] = *(const short8*)(pB[nt][1] + ko);
        }
        #pragma unroll
        for (int mt = 0; mt < 2; ++mt)
            #pragma unroll
            for (int nt = 0; nt < 4; ++nt) {
                acc[mt][nt] = mfma16(Af[mt][0], Bf[nt][0], acc[mt][nt]);
                acc[mt][nt] = mfma16(Af[mt][0], Bf[nt][1], acc[mt][nt]);
                acc[mt][nt] = mfma16(Af[mt][1], Bf[nt][0], acc[mt][nt]);
            }
    }
    #pragma unroll
    for (int mt = 0; mt < 2; ++mt)
        #pragma unroll
        for (int nt = 0; nt < 4; ++nt)
            #pragma unroll
            for (int r = 0; r < 4; ++r) {
                int m = bm + mt * 16 + quad * 4 + r;
                int n = bn + nt * 16 + ln;
                float v = acc[mt][nt][r];
                if (mode == 0) {
                    Cout[(size_t)m * 512 + n] = v;
                } else if (mode == 1) {
                    if (m < 4096) Cout[2 * ((size_t)m * 512 + n)] = v;
                    else          Cout[2 * ((size_t)(m - 4096) * 512 + n) + 1] = v;
                } else {
                    if (m < 4096) Cout[(size_t)m * 512 + n] = v;
                }
            }
}

// ---------------- complex gate: oh' = oh*g / (1 + exp(-2g)) ----------------
__global__ __launch_bounds__(256) void gate_kernel(
    const us* __restrict__ A1h, const us* __restrict__ A1l,
    const float* __restrict__ G,
    us* __restrict__ A2h, us* __restrict__ A2l, int n)
{
    int idx = (blockIdx.x * 256 + threadIdx.x) * 4;
    if (idx >= n) return;
    float4 grv = *(const float4*)&G[idx];
    float4 giv = *(const float4*)&G[idx + n];
    short4v hrh = *(const short4v*)&A1h[idx];
    short4v hrl = *(const short4v*)&A1l[idx];
    short4v hih = *(const short4v*)&A1h[n + idx];
    short4v hil = *(const short4v*)&A1l[n + idx];
    float grs[4] = {grv.x, grv.y, grv.z, grv.w};
    float gis[4] = {giv.x, giv.y, giv.z, giv.w};
    us rh[4], rl[4], ih_[4], il_[4];
    #pragma unroll
    for (int k = 0; k < 4; ++k) {
        float gr = grs[k], gi = gis[k];
        float hr = bf2f((us)hrh[k]) + bf2f((us)hrl[k]);
        float hi = bf2f((us)hih[k]) + bf2f((us)hil[k]);
        float e = expf(-2.0f * gr);
        float sn, cs;
        sincosf(2.0f * gi, &sn, &cs);
        float dr = 1.0f + e * cs;
        float di = -e * sn;
        float nr = hr * gr - hi * gi;
        float ni = hr * gi + hi * gr;
        float inv = 1.0f / (dr * dr + di * di);
        float o2r = (nr * dr + ni * di) * inv;
        float o2i = (ni * dr - nr * di) * inv;
        us t = f2bf(o2r); rh[k] = t; rl[k] = f2bf(o2r - bf2f(t));
        t = f2bf(o2i); ih_[k] = t; il_[k] = f2bf(o2i - bf2f(t));
    }
    *(short4v*)&A2h[idx]     = *(short4v*)&rh[0];
    *(short4v*)&A2l[idx]     = *(short4v*)&rl[0];
    *(short4v*)&A2h[n + idx] = *(short4v*)&ih_[0];
    *(short4v*)&A2l[n + idx] = *(short4v*)&il_[0];
}

extern "C" void kernel_launch(void* const* d_in, const int* in_sizes, int n_in,
                              void* d_out, int out_size, void* d_ws, size_t ws_size,
                              hipStream_t stream)
{
    const float* x     = (const float*)d_in[0];
    const float* WQ    = (const float*)d_in[1];
    const float* WK    = (const float*)d_in[2];
    const float* WV    = (const float*)d_in[3];
    const float* theta = (const float*)d_in[4];
    const float* gamma = (const float*)d_in[5];
    const float* qk    = (const float*)d_in[7];
    const float* WO    = (const float*)d_in[8];
    const float* WG    = (const float*)d_in[9];
    float* out = (float*)d_out;

    const size_t N1 = (size_t)B_ * H_ * C_ * HW_;       // 2,097,152
    const size_t SQ = (size_t)B_ * H_ * C_ * 128;       // 4,194,304 shorts
    const size_t SV = (size_t)B_ * H_ * HW_ * C_;       // 2,097,152 shorts
    us* usw = (us*)d_ws;
    us *Qch = usw,            *Qcl = usw + SQ,
       *K1h = usw + 2 * SQ,   *K1l = usw + 3 * SQ,
       *VTh = usw + 4 * SQ,   *VTl = usw + 4 * SQ + SV; // shorts end at 5*N1 floats
    float* fw = (float*)d_ws;
    // A1 lives in its own region [5N1, 7N1): retention writes it while other
    // blocks still read Qch (cannot overlay Q).
    us *A1h = (us*)(fw + 5 * N1), *A1l = (us*)(fw + 6 * N1);
    // WT overlays dead K1 (wcvt runs after retention+reduce):
    us *WTGh = K1h,            *WTGl = K1h + 262144,
       *WTOh = K1h + 524288,  *WTOl = K1h + 786432;
    float *G   = fw + 7 * N1;                           // 2*N1 fp32
    us *A2h = (us*)(fw + 9 * N1), *A2l = (us*)(fw + 10 * N1);
    float *Pbuf = fw + 7 * N1;                          // 3*N1, dead before G/A2

    proj_kernel<<<dim3(C_ / 32, B_ * H_), 256, 0, stream>>>(
        x, WQ, WK, WV, theta, Qch, Qcl, K1h, K1l, VTh, VTl);
    retention_kernel<<<dim3(768), 256, 0, stream>>>(
        Qch, Qcl, K1h, K1l, VTh, VTl, Pbuf, A1h, A1l, gamma, qk);
    reduce_kernel<<<dim3(16, B_ * H_), 256, 0, stream>>>(Pbuf, A1h, A1l);
    wcvt_kernel<<<dim3(16, 16, 2), 256, 0, stream>>>(
        WG, WO, WTGh, WTGl, WTOh, WTOl);

    gemm_mfma_kernel<<<dim3(64, 8), 256, 0, stream>>>(
        A1h, A1l, WTGh, WTGl, G, 0);

    int n1i = (int)N1;
    gate_kernel<<<dim3(n1i / 1024), 256, 0, stream>>>(
        A1h, A1l, G, A2h, A2l, n1i);

    int outmode = (out_size >= (int)(2 * N1)) ? 1 : 2;
    gemm_mfma_kernel<<<dim3(64, 8), 256, 0, stream>>>(
        A2h, A2l, WTOh, WTOl, out, outmode);
}